// Round 11
// baseline (399.013 us; speedup 1.0000x reference)
//
#include <hip/hip_runtime.h>
#include <hip/hip_fp16.h>
#include <stdint.h>

#define K_    367
#define P_    217
#define Q_    721
#define QC    217
#define CPQ   (QC*QC)               // 47089 corner positions
#define CPQV  47092                 // corner stream stride per k (padded to /4)
#define TPQ   109368                // tail positions per k (217*504)
#define YSTR  47104                 // y plane stride (floats), 16B aligned
#define PQ_   (P_*Q_)               // 156457
#define TOT   ((long long)K_*PQ_)   // 57,419,719 entries
#define NC    ((long long)K_*CPQ)   // 17,281,663 corner entries
#define NTAIL ((long long)K_*TPQ)   // 40,138,056 tail entries
#define SL    (NTAIL/8)             // 5,017,257 entries per pack slice (8 slices exact)
#define NVC   (CPQV/4)              // 11773 vec outputs (corner)
#define NVT   (TPQ/4)               // 27342 vec outputs (tail)
#define NPAD  (3*K_)                // corner pad slots
#define LDSH  47092                 // halfs in LDS (94.2 KB) -> FULL plane coverage

// entry encoding: v = (idx*2) | (f16_bits(w) << 17)   [w>=0 -> sign bit free]
__device__ __forceinline__ uint32_t encode_entry(int i0, int i1, float wv) {
    uint32_t idx2 = ((uint32_t)(i0 * QC + i1)) << 1;
    uint32_t hb = (uint32_t)__half_as_ushort(__float2half(wv));
    return idx2 | (hb << 17);
}

// branchless gather: idx-byte-offset in bits[16:1], f16 weight bits in [31:17]
#define GATHER(X, ACC) { uint32_t x_ = (X); \
    float g_ = __half2float(*(const __half*)((const char*)ylds + (x_ & 0x1FFFEu))); \
    float w_ = __half2float(__ushort_as_half((unsigned short)(x_ >> 17))); \
    ACC = fmaf(w_, g_, ACC); }

#define FILL_LDS() { \
    const float4* s4_ = (const float4*)yplane; \
    __half2* d2_ = (__half2*)ylds; \
    for (int i_ = threadIdx.x; i_ < LDSH / 4; i_ += 1024) { \
        float4 v_ = s4_[i_]; \
        d2_[2 * i_]     = __floats2half2_rn(v_.x, v_.y); \
        d2_[2 * i_ + 1] = __floats2half2_rn(v_.z, v_.w); \
    } }

// ---------- pack CORNER entries only (strided raw runs of 217) + y0 copy +
// pads + zero y1..y4 + zero out. Tail packing is deferred into the fused iters.
__global__ __launch_bounds__(256) void pack_corner(
    const int2* __restrict__ ind, const float* __restrict__ w,
    const float* __restrict__ inp,
    uint32_t* __restrict__ cornerS, float* __restrict__ ybase,
    float* __restrict__ out)
{
    long long id = (long long)blockIdx.x * 256 + threadIdx.x;
    if (id < NC) {
        uint32_t o = (uint32_t)id;
        uint32_t k = o / (uint32_t)CPQ;           // magic-mul
        uint32_t r = o - k * (uint32_t)CPQ;
        uint32_t p = r / (uint32_t)QC;
        uint32_t q = r - p * (uint32_t)QC;
        long long raw = (long long)k * PQ_ + p * Q_ + q;
        unsigned long long rr =
            __builtin_nontemporal_load((const unsigned long long*)(ind + raw));
        float wv = __builtin_nontemporal_load(w + raw);
        cornerS[k * (uint32_t)CPQV + r] =
            encode_entry((int)(uint32_t)(rr & 0xFFFFFFFFull),
                         (int)(uint32_t)(rr >> 32), wv);
        return;
    }
    long long e = id - NC;
    if (e < CPQ) {                                // y0 corner copy (both batches)
        int o = (int)e;
        int p = o / QC, q = o - p * QC;
        ybase[o]        = inp[p * 256 + q];
        ybase[YSTR + o] = inp[65536 + p * 256 + q];
        return;
    }
    e -= CPQ;
    if (e < NPAD) {                               // pad slots: idx=0, w=+0 -> no-op
        int k = (int)(e / 3);
        cornerS[(long long)k * CPQV + CPQ + (int)(e - (long long)k * 3)] = 0u;
        return;
    }
    e -= NPAD;
    if (e < 8 * YSTR) {                           // zero y1..y4 (atomic targets)
        ybase[2 * YSTR + e] = 0.f;
        return;
    }
    e -= 8 * YSTR;
    if (e < 2 * PQ_) out[e] = 0.f;                // zero output
}

// ---------- fused corner iteration + tail-pack slice.
// grid (120,1,2). Gather: 1 unit per block (ob=lb%12, kc=lb/12, KS=10).
// Then ALL threads pack tail slice s = it*2 + z (grid-stride). No barrier between:
// waves drift from LDS-bound gathers into HBM-bound packing -> pipe overlap.
__global__ __launch_bounds__(1024) void iter_corner_fused(
    const uint32_t* __restrict__ cs,
    const int2* __restrict__ ind, const float* __restrict__ w,
    uint32_t* __restrict__ tailS,
    const float* __restrict__ yin, float* __restrict__ yout,
    const float* __restrict__ lam_p, int it)
{
    __shared__ __half ylds[LDSH];
    const int bz = blockIdx.z;
    const float* __restrict__ yplane = yin + (size_t)bz * YSTR;
    FILL_LDS();
    __syncthreads();
    const float ls = *lam_p;
    const int lb = blockIdx.x;
    const uint4* cs4 = (const uint4*)cs;

    // gather unit
    {
        int ob = lb % 12, kc = lb / 12;
        int k0 = kc * K_ / 10, k1 = (kc + 1) * K_ / 10;
        int ov = ob * 1024 + threadIdx.x;
        if (ov < NVC) {
            float a0 = 0.f, a1 = 0.f, a2 = 0.f, a3 = 0.f;
            const uint4* pp = cs4 + (long long)k0 * NVC + ov;
            #pragma unroll 8
            for (int k = k0; k < k1; ++k, pp += NVC) {
                uint4 v = *pp;
                GATHER(v.x, a0); GATHER(v.y, a1); GATHER(v.z, a2); GATHER(v.w, a3);
            }
            float* op = yout + (size_t)bz * YSTR + 4 * ov;
            atomicAdd(op + 0, a0 * ls);
            atomicAdd(op + 1, a1 * ls);
            atomicAdd(op + 2, a2 * ls);
            atomicAdd(op + 3, a3 * ls);
        }
    }

    // tail-pack slice (independent of gather output; completes before iter_final)
    {
        long long t0 = (long long)(it * 2 + bz) * SL;
        long long t1 = t0 + SL;
        for (long long t = t0 + (long long)lb * 1024 + threadIdx.x; t < t1;
             t += 120LL * 1024) {
            uint32_t tt = (uint32_t)t;
            uint32_t k = tt / (uint32_t)TPQ;       // magic-mul
            uint32_t r = tt - k * (uint32_t)TPQ;
            uint32_t p = r / 504u;
            uint32_t q2 = r - p * 504u;
            long long raw = (long long)k * PQ_ + p * Q_ + QC + q2;
            unsigned long long rr =
                __builtin_nontemporal_load((const unsigned long long*)(ind + raw));
            float wv = __builtin_nontemporal_load(w + raw);
            tailS[tt] = encode_entry((int)(uint32_t)(rr & 0xFFFFFFFFull),
                                     (int)(uint32_t)(rr >> 32), wv);
        }
    }
}

// ---------- final iteration: corner half from corner stream, tail from tail stream
// grid: (117, 1, 2); nunits = 39*KS(6) = 234 -> exactly 2 units per block.
__global__ __launch_bounds__(1024) void iter_final(
    const uint32_t* __restrict__ cs, const uint32_t* __restrict__ ts,
    const float* __restrict__ yin, float* __restrict__ out,
    const float* __restrict__ lam_p, int KS)
{
    __shared__ __half ylds[LDSH];
    const int bz = blockIdx.z;
    const float* __restrict__ yplane = yin + (size_t)bz * YSTR;
    FILL_LDS();
    __syncthreads();
    const int NV = NVC + NVT;
    const int gx = (NV + 1023) / 1024;
    const int nunits = gx * KS;
    const float ls = *lam_p;
    for (int unit = blockIdx.x; unit < nunits; unit += gridDim.x) {
        int ob = unit % gx, kc = unit / gx;
        int ov = ob * 1024 + threadIdx.x;
        if (ov >= NV) continue;
        bool corner = ov < NVC;
        int lv = corner ? ov : ov - NVC;
        int stride = corner ? NVC : NVT;
        const uint4* base = corner ? (const uint4*)cs : (const uint4*)ts;
        int k0 = kc * K_ / KS, k1 = (kc + 1) * K_ / KS;
        float a0 = 0.f, a1 = 0.f, a2 = 0.f, a3 = 0.f;
        const uint4* pp = base + (long long)k0 * stride + lv;
        #pragma unroll 8
        for (int k = k0; k < k1; ++k, pp += stride) {
            uint4 v = *pp;
            GATHER(v.x, a0); GATHER(v.y, a1); GATHER(v.z, a2); GATHER(v.w, a3);
        }
        float acc[4] = {a0, a1, a2, a3};
        int o0 = 4 * lv;
        #pragma unroll
        for (int j = 0; j < 4; ++j) {
            int oo = o0 + j;
            int pos;
            if (corner) {
                if (oo >= CPQ) continue;          // pad slot
                int p = oo / QC; pos = p * Q_ + (oo - p * QC);
            } else {
                int p = oo / 504; pos = p * Q_ + QC + (oo - p * 504);
            }
            atomicAdd(&out[(size_t)bz * PQ_ + pos], acc[j] * ls);
        }
    }
}

extern "C" void kernel_launch(void* const* d_in, const int* in_sizes, int n_in,
                              void* d_out, int out_size, void* d_ws, size_t ws_size,
                              hipStream_t stream)
{
    const float* inp = (const float*)d_in[0];
    const int2*  ind = (const int2*)d_in[1];
    const float* w1  = (const float*)d_in[2];
    const float* lam = (const float*)d_in[3];
    float* out = (float*)d_out;

    size_t cbytes = ((((size_t)K_ * CPQV) * 4) + 255) & ~(size_t)255;
    size_t tbytes = ((((size_t)K_ * TPQ) * 4) + 255) & ~(size_t)255;
    size_t YB = (size_t)(2 * YSTR) * sizeof(float);
    if (ws_size < cbytes + tbytes + 5 * YB) return;   // ws has always been ample

    uint8_t* ws = (uint8_t*)d_ws;
    uint32_t* cornerS = (uint32_t*)ws;
    uint32_t* tailS   = (uint32_t*)(ws + cbytes);
    float* ybase = (float*)(ws + cbytes + tbytes);
    float* y[5];
    for (int i = 0; i < 5; ++i) y[i] = ybase + (size_t)i * (2 * YSTR);

    // setup: pack corner stream + y0 copy + pads + zero y1..y4 + zero out
    long long nwork = NC + CPQ + NPAD + 8LL * YSTR + 2LL * PQ_;
    unsigned nb = (unsigned)((nwork + 255) / 256);
    pack_corner<<<dim3(nb), 256, 0, stream>>>(ind, w1, inp, cornerS, ybase, out);

    // 4 fused corner iterations, each also packing 1/4 of the tail stream
    dim3 gC(120, 1, 2), gF(117, 1, 2);
    for (int it = 0; it < 4; ++it)
        iter_corner_fused<<<gC, 1024, 0, stream>>>(cornerS, ind, w1, tailS,
                                                   y[it], y[it + 1], lam, it);
    iter_final<<<gF, 1024, 0, stream>>>(cornerS, tailS, y[4], out, lam, 6);
}

// Round 12
// 349.799 us; speedup vs baseline: 1.1407x; 1.1407x over previous
//
#include <hip/hip_runtime.h>
#include <hip/hip_fp16.h>
#include <stdint.h>

#define K_    367
#define P_    217
#define Q_    721
#define QC    217
#define CPQ   (QC*QC)               // 47089 corner positions
#define CPQV  47092                 // corner stream stride per k (padded to /4)
#define TPQ   109368                // tail positions per k (217*504)
#define YSTR  47104                 // y plane stride (floats), 16B aligned
#define PQ_   (P_*Q_)               // 156457
#define TOT   ((long long)K_*PQ_)   // 57,419,719 entries
#define NC    ((long long)K_*CPQ)   // 17,281,663 corner entries
#define NVC   (CPQV/4)              // 11773 vec outputs (corner)
#define NVT   (TPQ/4)               // 27342 vec outputs (tail)
#define NPAD  (3*K_)                // corner pad slots
#define LDSH  47092                 // halfs in LDS (94.2 KB) -> FULL plane coverage

// entry encoding (corner stream): v = (idx*2) | (f16_bits(w) << 17)  [w>=0]
__device__ __forceinline__ uint32_t encode_entry(int i0, int i1, float wv) {
    uint32_t idx2 = ((uint32_t)(i0 * QC + i1)) << 1;
    uint32_t hb = (uint32_t)__half_as_ushort(__float2half(wv));
    return idx2 | (hb << 17);
}

// branchless gather: idx-byte-offset in bits[16:1], f16 weight bits in [31:17]
#define GATHER(X, ACC) { uint32_t x_ = (X); \
    float g_ = __half2float(*(const __half*)((const char*)ylds + (x_ & 0x1FFFEu))); \
    float w_ = __half2float(__ushort_as_half((unsigned short)(x_ >> 17))); \
    ACC = fmaf(w_, g_, ACC); }

#define FILL_LDS() { \
    const float4* s4_ = (const float4*)yplane; \
    __half2* d2_ = (__half2*)ylds; \
    for (int i_ = threadIdx.x; i_ < LDSH / 4; i_ += 1024) { \
        float4 v_ = s4_[i_]; \
        d2_[2 * i_]     = __floats2half2_rn(v_.x, v_.y); \
        d2_[2 * i_ + 1] = __floats2half2_rn(v_.z, v_.w); \
    } }

// ---------- pack CORNER entries only (runs of 217 within 721-rows; contiguous
// 1736B reads) + y0 copy + pads + zero y1..y4 + zero out. NO tail pack: the
// tail stream is consumed once -> iter_final reads raw ind/w directly.
__global__ __launch_bounds__(256) void pack_corner(
    const int2* __restrict__ ind, const float* __restrict__ w,
    const float* __restrict__ inp,
    uint32_t* __restrict__ cornerS, float* __restrict__ ybase,
    float* __restrict__ out)
{
    long long id = (long long)blockIdx.x * 256 + threadIdx.x;
    if (id < NC) {
        uint32_t o = (uint32_t)id;
        uint32_t k = o / (uint32_t)CPQ;           // magic-mul
        uint32_t r = o - k * (uint32_t)CPQ;
        uint32_t p = r / (uint32_t)QC;
        uint32_t q = r - p * (uint32_t)QC;
        long long raw = (long long)k * PQ_ + p * Q_ + q;
        unsigned long long rr =
            __builtin_nontemporal_load((const unsigned long long*)(ind + raw));
        float wv = __builtin_nontemporal_load(w + raw);
        cornerS[k * (uint32_t)CPQV + r] =
            encode_entry((int)(uint32_t)(rr & 0xFFFFFFFFull),
                         (int)(uint32_t)(rr >> 32), wv);
        return;
    }
    long long e = id - NC;
    if (e < CPQ) {                                // y0 corner copy (both batches)
        int o = (int)e;
        int p = o / QC, q = o - p * QC;
        ybase[o]        = inp[p * 256 + q];
        ybase[YSTR + o] = inp[65536 + p * 256 + q];
        return;
    }
    e -= CPQ;
    if (e < NPAD) {                               // pad slots: idx=0, w=+0 -> no-op
        int k = (int)(e / 3);
        cornerS[(long long)k * CPQV + CPQ + (int)(e - (long long)k * 3)] = 0u;
        return;
    }
    e -= NPAD;
    if (e < 8 * YSTR) {                           // zero y1..y4 (atomic targets)
        ybase[2 * YSTR + e] = 0.f;
        return;
    }
    e -= 8 * YSTR;
    if (e < 2 * PQ_) out[e] = 0.f;                // zero output
}

// ---------- corner iteration (round-9 proven, unchanged)
// grid: (120, 1, 2); nunits = 12*KS(10) = 120 -> exactly 1 unit per block.
__global__ __launch_bounds__(1024) void iter_corner(
    const uint32_t* __restrict__ cs, const float* __restrict__ yin,
    float* __restrict__ yout, const float* __restrict__ lam_p, int KS)
{
    __shared__ __half ylds[LDSH];
    const int bz = blockIdx.z;
    const float* __restrict__ yplane = yin + (size_t)bz * YSTR;
    FILL_LDS();
    __syncthreads();
    const int gx = (NVC + 1023) / 1024;
    const int nunits = gx * KS;
    const float ls = *lam_p;
    const uint4* cs4 = (const uint4*)cs;
    for (int unit = blockIdx.x; unit < nunits; unit += gridDim.x) {
        int ob = unit % gx, kc = unit / gx;
        int ov = ob * 1024 + threadIdx.x;
        if (ov >= NVC) continue;
        int k0 = kc * K_ / KS, k1 = (kc + 1) * K_ / KS;
        float a0 = 0.f, a1 = 0.f, a2 = 0.f, a3 = 0.f;
        const uint4* pp = cs4 + (long long)k0 * NVC + ov;
        #pragma unroll 8
        for (int k = k0; k < k1; ++k, pp += NVC) {
            uint4 v = *pp;
            GATHER(v.x, a0); GATHER(v.y, a1); GATHER(v.z, a2); GATHER(v.w, a3);
        }
        float* op = yout + (size_t)bz * YSTR + 4 * ov;
        atomicAdd(op + 0, a0 * ls);
        atomicAdd(op + 1, a1 * ls);
        atomicAdd(op + 2, a2 * ls);
        atomicAdd(op + 3, a3 * ls);
    }
}

// ---------- final iteration: corner half from packed corner stream;
// TAIL half reads RAW ind/w directly (dense 32B+16B per k; 504%4==0 so a
// vec-4 unit never crosses a run boundary). No nt hint here: the two batch
// grids read the same raw addresses concurrently -> L3 serves the 2nd batch.
// grid: (117, 1, 2); nunits = 39*KS(6) = 234 -> exactly 2 units per block.
__global__ __launch_bounds__(1024) void iter_final(
    const uint32_t* __restrict__ cs,
    const int2* __restrict__ ind, const float* __restrict__ w,
    const float* __restrict__ yin, float* __restrict__ out,
    const float* __restrict__ lam_p, int KS)
{
    __shared__ __half ylds[LDSH];
    const int bz = blockIdx.z;
    const float* __restrict__ yplane = yin + (size_t)bz * YSTR;
    FILL_LDS();
    __syncthreads();
    const int NV = NVC + NVT;
    const int gx = (NV + 1023) / 1024;
    const int nunits = gx * KS;
    const float ls = *lam_p;
    for (int unit = blockIdx.x; unit < nunits; unit += gridDim.x) {
        int ob = unit % gx, kc = unit / gx;
        int ov = ob * 1024 + threadIdx.x;
        if (ov >= NV) continue;
        int k0 = kc * K_ / KS, k1 = (kc + 1) * K_ / KS;
        float a0 = 0.f, a1 = 0.f, a2 = 0.f, a3 = 0.f;
        if (ov < NVC) {
            // corner half: packed stream (L3-hot, f16 weights)
            const uint4* pp = (const uint4*)cs + (long long)k0 * NVC + ov;
            #pragma unroll 8
            for (int k = k0; k < k1; ++k, pp += NVC) {
                uint4 v = *pp;
                GATHER(v.x, a0); GATHER(v.y, a1); GATHER(v.z, a2); GATHER(v.w, a3);
            }
            float acc[4] = {a0, a1, a2, a3};
            int o0 = 4 * ov;
            #pragma unroll
            for (int j = 0; j < 4; ++j) {
                int oo = o0 + j;
                if (oo >= CPQ) continue;          // pad slot
                int p = oo / QC;
                int pos = p * Q_ + (oo - p * QC);
                atomicAdd(&out[(size_t)bz * PQ_ + pos], acc[j] * ls);
            }
        } else {
            // tail half: raw ind/w (f32 weights)
            int lv = ov - NVC;
            int t = 4 * lv;                       // tail position, 504%4==0
            int p = t / 504;
            int q2 = t - p * 504;
            long long rawb = (long long)p * Q_ + QC + q2;
            const int2*  ip = ind + (long long)k0 * PQ_ + rawb;
            const float* wp = w   + (long long)k0 * PQ_ + rawb;
            #pragma unroll 4
            for (int k = k0; k < k1; ++k, ip += PQ_, wp += PQ_) {
                uint4 ia, ib; float4 wv;
                __builtin_memcpy(&ia, ip, 16);        // entries 0,1 (i0,i1,i0,i1)
                __builtin_memcpy(&ib, ip + 2, 16);    // entries 2,3
                __builtin_memcpy(&wv, wp, 16);        // 4 f32 weights
                a0 = fmaf(wv.x, __half2float(ylds[ia.x * QC + ia.y]), a0);
                a1 = fmaf(wv.y, __half2float(ylds[ia.z * QC + ia.w]), a1);
                a2 = fmaf(wv.z, __half2float(ylds[ib.x * QC + ib.y]), a2);
                a3 = fmaf(wv.w, __half2float(ylds[ib.z * QC + ib.w]), a3);
            }
            float acc[4] = {a0, a1, a2, a3};
            #pragma unroll
            for (int j = 0; j < 4; ++j) {
                int pos = p * Q_ + QC + q2 + j;   // same run for all 4
                atomicAdd(&out[(size_t)bz * PQ_ + pos], acc[j] * ls);
            }
        }
    }
}

extern "C" void kernel_launch(void* const* d_in, const int* in_sizes, int n_in,
                              void* d_out, int out_size, void* d_ws, size_t ws_size,
                              hipStream_t stream)
{
    const float* inp = (const float*)d_in[0];
    const int2*  ind = (const int2*)d_in[1];
    const float* w1  = (const float*)d_in[2];
    const float* lam = (const float*)d_in[3];
    float* out = (float*)d_out;

    size_t cbytes = ((((size_t)K_ * CPQV) * 4) + 255) & ~(size_t)255;
    size_t YB = (size_t)(2 * YSTR) * sizeof(float);
    if (ws_size < cbytes + 5 * YB) return;        // ws has always been ample

    uint8_t* ws = (uint8_t*)d_ws;
    uint32_t* cornerS = (uint32_t*)ws;
    float* ybase = (float*)(ws + cbytes);
    float* y[5];
    for (int i = 0; i < 5; ++i) y[i] = ybase + (size_t)i * (2 * YSTR);

    // setup: pack corner stream + y0 copy + pads + zero y1..y4 + zero out
    long long nwork = NC + CPQ + NPAD + 8LL * YSTR + 2LL * PQ_;
    unsigned nb = (unsigned)((nwork + 255) / 256);
    pack_corner<<<dim3(nb), 256, 0, stream>>>(ind, w1, inp, cornerS, ybase, out);

    dim3 gC(120, 1, 2), gF(117, 1, 2);
    for (int it = 0; it < 4; ++it)
        iter_corner<<<gC, 1024, 0, stream>>>(cornerS, y[it], y[it + 1], lam, 10);
    iter_final<<<gF, 1024, 0, stream>>>(cornerS, ind, w1, y[4], out, lam, 6);
}